// Round 7
// baseline (173.768 us; speedup 1.0000x reference)
//
#include <hip/hip_runtime.h>

#define B_    2
#define T_    2048
#define C_    1024
#define H_    16
#define DH_   64
#define M_    (B_ * T_)        // 4096 tokens
#define NQKV  (3 * C_)         // 3072

typedef __bf16 bf16;
typedef __bf16 bf16x4 __attribute__((ext_vector_type(4)));
typedef __bf16 bf16x8 __attribute__((ext_vector_type(8)));
typedef float  f32x4  __attribute__((ext_vector_type(4)));

// async global->LDS, 16B per lane (global_load_lds_dwordx4).
// LDS dest must be wave-uniform base + lane*16 (no per-lane scatter).
__device__ __forceinline__ void async16(const void* g, void* l) {
  __builtin_amdgcn_global_load_lds(
      (const __attribute__((address_space(1))) void*)g,
      (__attribute__((address_space(3))) void*)l, 16, 0, 0);
}

// ---------------------------------------------------------------- converts
__global__ __launch_bounds__(256) void cvt_bf16_k(const float* __restrict__ in,
                                                  bf16* __restrict__ out) {
  const int i = (blockIdx.x * 256 + threadIdx.x) * 4;
  float4 v = *(const float4*)(in + i);
  bf16x4 o;
  o[0] = (bf16)v.x; o[1] = (bf16)v.y; o[2] = (bf16)v.z; o[3] = (bf16)v.w;
  *(bf16x4*)(out + i) = o;
}

// in: fp32 [R x C] row-major; out: bf16 [C x R] (i.e. transposed), both coalesced
__global__ __launch_bounds__(256) void transpose_cvt(const float* __restrict__ in,
                                                     bf16* __restrict__ out,
                                                     int R, int C) {
  __shared__ float tile[32][33];
  const int c0 = blockIdx.x * 32, r0 = blockIdx.y * 32;
  const int tx = threadIdx.x, ty = threadIdx.y;
#pragma unroll
  for (int j = 0; j < 4; j++)
    tile[ty + j * 8][tx] = in[(size_t)(r0 + ty + j * 8) * C + c0 + tx];
  __syncthreads();
#pragma unroll
  for (int j = 0; j < 4; j++)
    out[(size_t)(c0 + ty + j * 8) * R + r0 + tx] = (bf16)tile[tx][ty + j * 8];
}

// ---------------------------------------------------------------- GEMM (r6)
// C[M,N] = A[M,K=1024] * Bt[N,K]^T (+bias). Tile BM x 128, BK=64, 4 waves.
// LDS rows 128B; groups XOR-swizzled by row&7. Single-buffered (cross-block
// overlap hides the drain; explicit dbuf regressed in r3).
template <int EPI, int BM>
__global__ __launch_bounds__(256) void gemm_k(
    const bf16* __restrict__ A, const bf16* __restrict__ Bt,
    const float* __restrict__ bias, float* __restrict__ outF,
    bf16* __restrict__ qb, bf16* __restrict__ kb, bf16* __restrict__ vtb) {
  constexpr int K = 1024;
  constexpr int MI = BM / 32;                    // m-frags per wave
  __shared__ alignas(16) bf16 As[BM * 64];
  __shared__ alignas(16) bf16 Bs[128 * 64];
  const int tid = threadIdx.x;
  const int lane = tid & 63, wv = tid >> 6;
  const int l15 = lane & 15, quad = lane >> 4;
  const int wm = (wv >> 1) * (BM / 2), wn = (wv & 1) * 64;
  const int m0 = blockIdx.x * BM, n0 = blockIdx.y * 128;

  f32x4 acc[MI][4] = {};

  const int srow = tid >> 3;                     // 0..31 (+32/call)
  const int sgb = ((tid & 7) ^ (srow & 7)) * 8;
  const bf16* ga = A + (size_t)(m0 + srow) * K + sgb;
  const bf16* gb = Bt + (size_t)(n0 + srow) * K + sgb;
  const int swz = l15 & 7;                       // read-side swizzle key

  for (int it = 0; it < K / 64; ++it) {
    const int k0 = it * 64;
#pragma unroll
    for (int c = 0; c < BM / 32; c++)            // A: BM rows, 32/call
      async16(ga + k0 + (size_t)(c * 32) * K, As + tid * 8 + c * 2048);
#pragma unroll
    for (int c = 0; c < 4; c++)                  // B: 128 rows
      async16(gb + k0 + (size_t)(c * 32) * K, Bs + tid * 8 + c * 2048);
    __syncthreads();
    bf16x8 af[2][MI], bfr[2][4];
#pragma unroll
    for (int kk = 0; kk < 2; kk++) {
#pragma unroll
      for (int i = 0; i < MI; i++)
        af[kk][i] = *(const bf16x8*)(As + (wm + i * 16 + l15) * 64 +
                                     (((kk * 4 + quad) ^ swz) << 3));
#pragma unroll
      for (int j = 0; j < 4; j++)
        bfr[kk][j] = *(const bf16x8*)(Bs + (wn + j * 16 + l15) * 64 +
                                      (((kk * 4 + quad) ^ swz) << 3));
    }
#pragma unroll
    for (int kk = 0; kk < 2; kk++)
#pragma unroll
      for (int i = 0; i < MI; i++)
#pragma unroll
        for (int j = 0; j < 4; j++)
          acc[i][j] = __builtin_amdgcn_mfma_f32_16x16x32_bf16(
              af[kk][i], bfr[kk][j], acc[i][j], 0, 0, 0);
    __syncthreads();
  }

  // epilogue: C/D layout col=lane&15, row=quad*4+reg
#pragma unroll
  for (int i = 0; i < MI; i++) {
#pragma unroll
    for (int j = 0; j < 4; j++) {
      const int gcol = n0 + wn + j * 16 + l15;
      const float bv = bias[gcol];
#pragma unroll
      for (int r = 0; r < 4; r++) {
        const int grow = m0 + wm + i * 16 + quad * 4 + r;
        float v = acc[i][j][r] + bv;
        if constexpr (EPI == 0) {
          const int which = gcol >> 10;          // 0=Q 1=K 2=V
          const int hn = gcol & 1023;
          const int h = hn >> 6, d = hn & 63;
          const int bb = grow >> 11, t = grow & 2047;
          const int head = bb * 16 + h;          // 0..31
          if (which == 0)
            qb[head * 131072 + t * 64 + d] = (bf16)(v * 0.1803368801f); // 1/8 * log2(e)
          else if (which == 1)
            kb[head * 131072 + t * 64 + d] = (bf16)v;
          else
            vtb[head * 131072 + d * 2048 + t] = (bf16)v;
        } else {
          outF[(size_t)grow * 1024 + gcol] = v;
        }
      }
    }
  }
}

// ---------------------------------------------------------------- flash attention
// 512 blocks x 512 threads = 2 blocks/CU (cross-block overlap fills the
// per-iter chain stalls that r6's 1-block/CU layout exposed). One q-tile of
// 128 per block; blocks b and b+256 are complementary (x, 15-x) so each CU
// gets exactly 17 kt128-iters. Head = fn(b) with b&7 = XCD pin (r4: FETCH
// 63->12MB). LDS 64KB/block: Ks single 16K (kf regs + 2nd barrier make
// overwrite safe), Vs double 32K, Ps 2K/wave reused in two kt64 half-rounds.
// Swapped-operand MFMAs: St = K*Q^T, O^T = V*P^T; each lane owns ONE q row.
__global__ __launch_bounds__(512, 4) void attn_k(const bf16* __restrict__ Q,
                                                 const bf16* __restrict__ K,
                                                 const bf16* __restrict__ Vt,
                                                 bf16* __restrict__ O) {
  __shared__ alignas(16) bf16 Ks[128 * 64];      // [kt][d], 8-group swizzle
  __shared__ alignas(16) bf16 Vs[2][64 * 128];   // [d][kt], 16-group swizzle
  __shared__ alignas(16) bf16 Ps[8][16 * 64];    // per-wave half-P^T (kt 64)
  const int tid = threadIdx.x, lane = tid & 63, wv = tid >> 6;  // wv 0..7
  const int l15 = lane & 15, quad = lane >> 4;

  const int b = blockIdx.x;                      // 0..511
  const int sH = b >> 8, i = b & 255;
  const int bh = (i & 7) | (((i >> 3) & 3) << 3);  // head 0..31, b&7 = XCD
  const int x = i >> 5;                          // 0..7
  const int qJ = sH ? (15 - x) : x;
  const int q0 = qJ * 128;
  const int nIter = qJ + 1;

  const bf16* Qb = Q + (size_t)bh * 131072;
  const bf16* Kb = K + (size_t)bh * 131072;
  const bf16* Vb = Vt + (size_t)bh * 131072;

  // staging addresses. K tile: 128 rows x 128B, 2 calls of 64 rows.
  const int krow = tid >> 3;                     // 0..63
  const int kg = (tid & 7) ^ (krow & 7);
  const bf16* gk = Kb + krow * 64 + kg * 8;
  // V tile: 64 rows x 256B (16 groups), 2 calls of 32 rows.
  const int vrow = tid >> 4;                     // 0..31
  const int vg = (tid & 15) ^ (vrow & 15);
  const bf16* gv = Vb + vrow * 2048 + vg * 8;

  const int swz7 = l15 & 7;                      // K/P read swizzle key
  bf16* Pw = Ps[wv];
  const int bb = bh >> 4, h = bh & 15;

  const int q = q0 + wv * 16 + l15;              // this lane's q row
  bf16x8 aq0 = *(const bf16x8*)(Qb + q * 64 + quad * 8);       // B[n=q][k=d]
  bf16x8 aq1 = *(const bf16x8*)(Qb + q * 64 + 32 + quad * 8);

  f32x4 o[4] = {};                               // O^T: d = nf*16+quad*4+r
  float m = -3.0e38f, lsum = 0.f;

  // prologue: stage kt-tile 0
  async16(gk, &Ks[tid * 8]);
  async16(gk + 64 * 64, &Ks[tid * 8 + 4096]);
  async16(gv, &Vs[0][tid * 8]);
  async16(gv + 32 * 2048, &Vs[0][tid * 8 + 4096]);

  for (int it = 0; it < nIter; ++it) {
    __syncthreads();                             // K(it), V(it) resident
    const bf16* Vc = Vs[it & 1];

    // all kf reads must complete before barrier2 (then Ks may be overwritten)
    bf16x8 kf0[8], kf1[8];
#pragma unroll
    for (int nf = 0; nf < 8; nf++)
      kf0[nf] = *(const bf16x8*)(Ks + (nf * 16 + l15) * 64 + ((quad ^ swz7) << 3));
#pragma unroll
    for (int nf = 0; nf < 8; nf++)
      kf1[nf] = *(const bf16x8*)(Ks + (nf * 16 + l15) * 64 + (((4 + quad) ^ swz7) << 3));

    // St kc0 while waiting: s[nf][r] = S[kt = it*128+nf*16+quad*4+r][q]
    f32x4 s[8] = {};
#pragma unroll
    for (int nf = 0; nf < 8; nf++)
      s[nf] = __builtin_amdgcn_mfma_f32_16x16x32_bf16(kf0[nf], aq0, s[nf], 0, 0, 0);

    __syncthreads();                             // all waves done reading Ks
    if (it + 1 < nIter) {                        // prefetch into Ks / other Vs
      const int kt1 = (it + 1) * 128;
      async16(gk + kt1 * 64, &Ks[tid * 8]);
      async16(gk + kt1 * 64 + 64 * 64, &Ks[tid * 8 + 4096]);
      async16(gv + kt1, &Vs[(it + 1) & 1][tid * 8]);
      async16(gv + kt1 + 32 * 2048, &Vs[(it + 1) & 1][tid * 8 + 4096]);
    }

#pragma unroll
    for (int nf = 0; nf < 8; nf++)
      s[nf] = __builtin_amdgcn_mfma_f32_16x16x32_bf16(kf1[nf], aq1, s[nf], 0, 0, 0);

    if (it == nIter - 1) {                       // diagonal tile mask
#pragma unroll
      for (int nf = 0; nf < 8; nf++)
#pragma unroll
        for (int r = 0; r < 4; r++) {
          const int kt = it * 128 + nf * 16 + quad * 4 + r;
          if (kt > q) s[nf][r] = -3.0e38f;
        }
    }

    // per-lane online softmax (32 local kt + cross-quad combine)
    float mx = s[0][0];
#pragma unroll
    for (int nf = 0; nf < 8; nf++)
#pragma unroll
      for (int r = 0; r < 4; r++) mx = fmaxf(mx, s[nf][r]);
    mx = fmaxf(mx, __shfl_xor(mx, 16));
    mx = fmaxf(mx, __shfl_xor(mx, 32));
    const float mnew = fmaxf(m, mx);
    const float alpha = __builtin_amdgcn_exp2f(m - mnew);
    m = mnew;
    float ts = 0.f;
    bf16x4 p4[8];
#pragma unroll
    for (int nf = 0; nf < 8; nf++)
#pragma unroll
      for (int r = 0; r < 4; r++) {
        const float pv = __builtin_amdgcn_exp2f(s[nf][r] - mnew);
        ts += pv;
        p4[nf][r] = (bf16)pv;
      }
    ts += __shfl_xor(ts, 16);
    ts += __shfl_xor(ts, 32);
    lsum = lsum * alpha + ts;
#pragma unroll
    for (int nf = 0; nf < 4; nf++)
#pragma unroll
      for (int r = 0; r < 4; r++) o[nf][r] *= alpha;

    // two kt64 half-rounds through the 2K/wave P buffer (same-wave DS order
    // makes the reuse safe; no barrier — Pw is per-wave).
#pragma unroll
    for (int half = 0; half < 2; half++) {
#pragma unroll
      for (int nf = 0; nf < 4; nf++)
        *(bf16x4*)(Pw + l15 * 64 + ((((nf << 1) | (quad >> 1)) ^ swz7) << 3) +
                   ((quad & 1) << 2)) = p4[half * 4 + nf];
      bf16x8 pb0 = *(const bf16x8*)(Pw + l15 * 64 + ((quad ^ swz7) << 3));
      bf16x8 pb1 = *(const bf16x8*)(Pw + l15 * 64 + (((4 + quad) ^ swz7) << 3));
#pragma unroll
      for (int kc = 0; kc < 2; kc++) {
        bf16x8 pb = kc ? pb1 : pb0;
        const int kcg = half * 2 + kc;           // global kt32-chunk 0..3
#pragma unroll
        for (int nf = 0; nf < 4; nf++) {
          bf16x8 vf = *(const bf16x8*)(Vc + (nf * 16 + l15) * 128 +
                                       (((kcg * 4 + quad) ^ l15) << 3));
          o[nf] = __builtin_amdgcn_mfma_f32_16x16x32_bf16(vf, pb, o[nf], 0, 0, 0);
        }
      }
    }
  }

  // epilogue: lane owns q; d = nf*16+quad*4+r -> 4x 8B stores
  const float inv = 1.0f / lsum;
#pragma unroll
  for (int nf = 0; nf < 4; nf++) {
    bf16x4 ov;
#pragma unroll
    for (int r = 0; r < 4; r++) ov[r] = (bf16)(o[nf][r] * inv);
    *(bf16x4*)(O + (size_t)(bb * 2048 + q) * 1024 + h * 64 + nf * 16 + quad * 4) = ov;
  }
}

// ---------------------------------------------------------------- launch
extern "C" void kernel_launch(void* const* d_in, const int* in_sizes, int n_in,
                              void* d_out, int out_size, void* d_ws, size_t ws_size,
                              hipStream_t stream) {
  const float* x     = (const float*)d_in[0];
  const float* Wqkv  = (const float*)d_in[1];
  const float* bqkv  = (const float*)d_in[2];
  const float* Wproj = (const float*)d_in[3];
  const float* bproj = (const float*)d_in[4];
  float* out = (float*)d_out;

  char* p = (char*)d_ws;
  bf16* xbf    = (bf16*)p; p += (size_t)M_ * C_ * 2;     // 8 MB
  bf16* wqkvT  = (bf16*)p; p += (size_t)NQKV * C_ * 2;   // 6 MB
  bf16* wprojT = (bf16*)p; p += (size_t)C_ * C_ * 2;     // 2 MB
  bf16* Qb     = (bf16*)p; p += (size_t)M_ * C_ * 2;     // 8 MB
  bf16* Kb     = (bf16*)p; p += (size_t)M_ * C_ * 2;     // 8 MB
  bf16* Vtb    = (bf16*)p; p += (size_t)M_ * C_ * 2;     // 8 MB
  bf16* AO     = (bf16*)p;                               // 8 MB (total 48 MB)

  cvt_bf16_k<<<M_ * C_ / 1024, 256, 0, stream>>>(x, xbf);
  transpose_cvt<<<dim3(NQKV / 32, C_ / 32), dim3(32, 8), 0, stream>>>(Wqkv, wqkvT, C_, NQKV);
  transpose_cvt<<<dim3(C_ / 32, C_ / 32), dim3(32, 8), 0, stream>>>(Wproj, wprojT, C_, C_);

  gemm_k<0, 128><<<dim3(M_ / 128, NQKV / 128), 256, 0, stream>>>(
      xbf, wqkvT, bqkv, nullptr, Qb, Kb, Vtb);

  attn_k<<<512, 512, 0, stream>>>(Qb, Kb, Vtb, AO);

  gemm_k<1, 64><<<dim3(M_ / 64, C_ / 128), 256, 0, stream>>>(
      AO, wprojT, bproj, out, nullptr, nullptr, nullptr);
}

// Round 8
// 169.060 us; speedup vs baseline: 1.0278x; 1.0278x over previous
//
#include <hip/hip_runtime.h>

#define B_    2
#define T_    2048
#define C_    1024
#define H_    16
#define DH_   64
#define M_    (B_ * T_)        // 4096 tokens
#define NQKV  (3 * C_)         // 3072

typedef __bf16 bf16;
typedef __bf16 bf16x4 __attribute__((ext_vector_type(4)));
typedef __bf16 bf16x8 __attribute__((ext_vector_type(8)));
typedef float  f32x4  __attribute__((ext_vector_type(4)));

// async global->LDS, 16B per lane (global_load_lds_dwordx4).
// LDS dest must be wave-uniform base + lane*16 (no per-lane scatter).
__device__ __forceinline__ void async16(const void* g, void* l) {
  __builtin_amdgcn_global_load_lds(
      (const __attribute__((address_space(1))) void*)g,
      (__attribute__((address_space(3))) void*)l, 16, 0, 0);
}

// ---------------------------------------------------------------- converts
__global__ __launch_bounds__(256) void cvt_bf16_k(const float* __restrict__ in,
                                                  bf16* __restrict__ out) {
  const int i = (blockIdx.x * 256 + threadIdx.x) * 4;
  float4 v = *(const float4*)(in + i);
  bf16x4 o;
  o[0] = (bf16)v.x; o[1] = (bf16)v.y; o[2] = (bf16)v.z; o[3] = (bf16)v.w;
  *(bf16x4*)(out + i) = o;
}

// in: fp32 [R x C] row-major; out: bf16 [C x R] (i.e. transposed), both coalesced
__global__ __launch_bounds__(256) void transpose_cvt(const float* __restrict__ in,
                                                     bf16* __restrict__ out,
                                                     int R, int C) {
  __shared__ float tile[32][33];
  const int c0 = blockIdx.x * 32, r0 = blockIdx.y * 32;
  const int tx = threadIdx.x, ty = threadIdx.y;
#pragma unroll
  for (int j = 0; j < 4; j++)
    tile[ty + j * 8][tx] = in[(size_t)(r0 + ty + j * 8) * C + c0 + tx];
  __syncthreads();
#pragma unroll
  for (int j = 0; j < 4; j++)
    out[(size_t)(c0 + ty + j * 8) * R + r0 + tx] = (bf16)tile[tx][ty + j * 8];
}

// ---------------------------------------------------------------- GEMM
// C[M,N] = A[M,K=1024] * Bt[N,K]^T (+bias). Tile BM x 128, BK=64, 4 waves
// (2x2 of (BM/2)x64). BM=64 for BOTH gemms: grid = 6 blocks/CU (QKV) /
// 2 blocks/CU (proj) -- r5/r7 showed the single-buffered K-loop needs
// cross-block TLP to hide the staging drain (3 blocks/CU left both pipes
// <35% busy). LDS 24KB -> exactly 6 fit. Rows 128B, groups XOR-swizzled by
// row&7 (2-way = free). V^T epilogue stores vectorized bf16x4 (t-contiguous).
template <int EPI, int BM>
__global__ __launch_bounds__(256) void gemm_k(
    const bf16* __restrict__ A, const bf16* __restrict__ Bt,
    const float* __restrict__ bias, float* __restrict__ outF,
    bf16* __restrict__ qb, bf16* __restrict__ kb, bf16* __restrict__ vtb) {
  constexpr int K = 1024;
  constexpr int MI = BM / 32;                    // m-frags per wave
  __shared__ alignas(16) bf16 As[BM * 64];
  __shared__ alignas(16) bf16 Bs[128 * 64];
  const int tid = threadIdx.x;
  const int lane = tid & 63, wv = tid >> 6;
  const int l15 = lane & 15, quad = lane >> 4;
  const int wm = (wv >> 1) * (BM / 2), wn = (wv & 1) * 64;
  const int m0 = blockIdx.x * BM, n0 = blockIdx.y * 128;

  f32x4 acc[MI][4] = {};

  const int srow = tid >> 3;                     // 0..31 (+32/call)
  const int sgb = ((tid & 7) ^ (srow & 7)) * 8;
  const bf16* ga = A + (size_t)(m0 + srow) * K + sgb;
  const bf16* gb = Bt + (size_t)(n0 + srow) * K + sgb;
  const int swz = l15 & 7;                       // read-side swizzle key

  for (int it = 0; it < K / 64; ++it) {
    const int k0 = it * 64;
#pragma unroll
    for (int c = 0; c < BM / 32; c++)            // A: BM rows, 32/call
      async16(ga + k0 + (size_t)(c * 32) * K, As + tid * 8 + c * 2048);
#pragma unroll
    for (int c = 0; c < 4; c++)                  // B: 128 rows
      async16(gb + k0 + (size_t)(c * 32) * K, Bs + tid * 8 + c * 2048);
    __syncthreads();
    bf16x8 af[2][MI], bfr[2][4];
#pragma unroll
    for (int kk = 0; kk < 2; kk++) {
#pragma unroll
      for (int i = 0; i < MI; i++)
        af[kk][i] = *(const bf16x8*)(As + (wm + i * 16 + l15) * 64 +
                                     (((kk * 4 + quad) ^ swz) << 3));
#pragma unroll
      for (int j = 0; j < 4; j++)
        bfr[kk][j] = *(const bf16x8*)(Bs + (wn + j * 16 + l15) * 64 +
                                      (((kk * 4 + quad) ^ swz) << 3));
    }
#pragma unroll
    for (int kk = 0; kk < 2; kk++)
#pragma unroll
      for (int i = 0; i < MI; i++)
#pragma unroll
        for (int j = 0; j < 4; j++)
          acc[i][j] = __builtin_amdgcn_mfma_f32_16x16x32_bf16(
              af[kk][i], bfr[kk][j], acc[i][j], 0, 0, 0);
    __syncthreads();
  }

  // epilogue: C/D layout col=lane&15, row=quad*4+reg
#pragma unroll
  for (int i = 0; i < MI; i++) {
#pragma unroll
    for (int j = 0; j < 4; j++) {
      const int gcol = n0 + wn + j * 16 + l15;
      const float bv = bias[gcol];
      const int trow = m0 + wm + i * 16 + quad * 4;   // grow base (4-aligned)
      if constexpr (EPI == 0) {
        const int which = gcol >> 10;            // 0=Q 1=K 2=V
        const int hn = gcol & 1023;
        const int h = hn >> 6, d = hn & 63;
        const int bb = trow >> 11, t = trow & 2047;
        const int head = bb * 16 + h;            // 0..31
        if (which == 0) {
#pragma unroll
          for (int r = 0; r < 4; r++)
            qb[head * 131072 + (t + r) * 64 + d] =
                (bf16)((acc[i][j][r] + bv) * 0.1803368801f); // 1/8 * log2(e)
        } else if (which == 1) {
#pragma unroll
          for (int r = 0; r < 4; r++)
            kb[head * 131072 + (t + r) * 64 + d] = (bf16)(acc[i][j][r] + bv);
        } else {
          bf16x4 pv;                             // t-contiguous in V^T [d][t]
#pragma unroll
          for (int r = 0; r < 4; r++) pv[r] = (bf16)(acc[i][j][r] + bv);
          *(bf16x4*)(vtb + head * 131072 + d * 2048 + t) = pv;
        }
      } else {
#pragma unroll
        for (int r = 0; r < 4; r++)
          outF[(size_t)(trow + r) * 1024 + gcol] = acc[i][j][r] + bv;
      }
    }
  }
}

// ---------------------------------------------------------------- flash attention
// (r7 structure, unchanged) 512 blocks x 512 threads = 2 blocks/CU. One
// q-tile of 128 per block; blocks b and b+256 complementary (x, 15-x) so each
// CU gets exactly 17 kt128-iters. b&7 = XCD head pin (FETCH 63->12MB in r4).
// LDS 64KB: Ks single 16K, Vs double 32K, Ps 2K/wave in two kt64 half-rounds.
// Swapped-operand MFMAs: St = K*Q^T, O^T = V*P^T; each lane owns ONE q row.
__global__ __launch_bounds__(512, 4) void attn_k(const bf16* __restrict__ Q,
                                                 const bf16* __restrict__ K,
                                                 const bf16* __restrict__ Vt,
                                                 bf16* __restrict__ O) {
  __shared__ alignas(16) bf16 Ks[128 * 64];      // [kt][d], 8-group swizzle
  __shared__ alignas(16) bf16 Vs[2][64 * 128];   // [d][kt], 16-group swizzle
  __shared__ alignas(16) bf16 Ps[8][16 * 64];    // per-wave half-P^T (kt 64)
  const int tid = threadIdx.x, lane = tid & 63, wv = tid >> 6;  // wv 0..7
  const int l15 = lane & 15, quad = lane >> 4;

  const int b = blockIdx.x;                      // 0..511
  const int sH = b >> 8, i = b & 255;
  const int bh = (i & 7) | (((i >> 3) & 3) << 3);  // head 0..31, b&7 = XCD
  const int x = i >> 5;                          // 0..7
  const int qJ = sH ? (15 - x) : x;
  const int q0 = qJ * 128;
  const int nIter = qJ + 1;

  const bf16* Qb = Q + (size_t)bh * 131072;
  const bf16* Kb = K + (size_t)bh * 131072;
  const bf16* Vb = Vt + (size_t)bh * 131072;

  const int krow = tid >> 3;                     // 0..63
  const int kg = (tid & 7) ^ (krow & 7);
  const bf16* gk = Kb + krow * 64 + kg * 8;
  const int vrow = tid >> 4;                     // 0..31
  const int vg = (tid & 15) ^ (vrow & 15);
  const bf16* gv = Vb + vrow * 2048 + vg * 8;

  const int swz7 = l15 & 7;                      // K/P read swizzle key
  bf16* Pw = Ps[wv];
  const int bb = bh >> 4, h = bh & 15;

  const int q = q0 + wv * 16 + l15;              // this lane's q row
  bf16x8 aq0 = *(const bf16x8*)(Qb + q * 64 + quad * 8);       // B[n=q][k=d]
  bf16x8 aq1 = *(const bf16x8*)(Qb + q * 64 + 32 + quad * 8);

  f32x4 o[4] = {};                               // O^T: d = nf*16+quad*4+r
  float m = -3.0e38f, lsum = 0.f;

  // prologue: stage kt-tile 0
  async16(gk, &Ks[tid * 8]);
  async16(gk + 64 * 64, &Ks[tid * 8 + 4096]);
  async16(gv, &Vs[0][tid * 8]);
  async16(gv + 32 * 2048, &Vs[0][tid * 8 + 4096]);

  for (int it = 0; it < nIter; ++it) {
    __syncthreads();                             // K(it), V(it) resident
    const bf16* Vc = Vs[it & 1];

    // all kf reads must complete before barrier2 (then Ks may be overwritten)
    bf16x8 kf0[8], kf1[8];
#pragma unroll
    for (int nf = 0; nf < 8; nf++)
      kf0[nf] = *(const bf16x8*)(Ks + (nf * 16 + l15) * 64 + ((quad ^ swz7) << 3));
#pragma unroll
    for (int nf = 0; nf < 8; nf++)
      kf1[nf] = *(const bf16x8*)(Ks + (nf * 16 + l15) * 64 + (((4 + quad) ^ swz7) << 3));

    // St kc0 while waiting: s[nf][r] = S[kt = it*128+nf*16+quad*4+r][q]
    f32x4 s[8] = {};
#pragma unroll
    for (int nf = 0; nf < 8; nf++)
      s[nf] = __builtin_amdgcn_mfma_f32_16x16x32_bf16(kf0[nf], aq0, s[nf], 0, 0, 0);

    __syncthreads();                             // all waves done reading Ks
    if (it + 1 < nIter) {                        // prefetch into Ks / other Vs
      const int kt1 = (it + 1) * 128;
      async16(gk + kt1 * 64, &Ks[tid * 8]);
      async16(gk + kt1 * 64 + 64 * 64, &Ks[tid * 8 + 4096]);
      async16(gv + kt1, &Vs[(it + 1) & 1][tid * 8]);
      async16(gv + kt1 + 32 * 2048, &Vs[(it + 1) & 1][tid * 8 + 4096]);
    }

#pragma unroll
    for (int nf = 0; nf < 8; nf++)
      s[nf] = __builtin_amdgcn_mfma_f32_16x16x32_bf16(kf1[nf], aq1, s[nf], 0, 0, 0);

    if (it == nIter - 1) {                       // diagonal tile mask
#pragma unroll
      for (int nf = 0; nf < 8; nf++)
#pragma unroll
        for (int r = 0; r < 4; r++) {
          const int kt = it * 128 + nf * 16 + quad * 4 + r;
          if (kt > q) s[nf][r] = -3.0e38f;
        }
    }

    // per-lane online softmax (32 local kt + cross-quad combine)
    float mx = s[0][0];
#pragma unroll
    for (int nf = 0; nf < 8; nf++)
#pragma unroll
      for (int r = 0; r < 4; r++) mx = fmaxf(mx, s[nf][r]);
    mx = fmaxf(mx, __shfl_xor(mx, 16));
    mx = fmaxf(mx, __shfl_xor(mx, 32));
    const float mnew = fmaxf(m, mx);
    const float alpha = __builtin_amdgcn_exp2f(m - mnew);
    m = mnew;
    float ts = 0.f;
    bf16x4 p4[8];
#pragma unroll
    for (int nf = 0; nf < 8; nf++)
#pragma unroll
      for (int r = 0; r < 4; r++) {
        const float pv = __builtin_amdgcn_exp2f(s[nf][r] - mnew);
        ts += pv;
        p4[nf][r] = (bf16)pv;
      }
    ts += __shfl_xor(ts, 16);
    ts += __shfl_xor(ts, 32);
    lsum = lsum * alpha + ts;
#pragma unroll
    for (int nf = 0; nf < 4; nf++)
#pragma unroll
      for (int r = 0; r < 4; r++) o[nf][r] *= alpha;

    // two kt64 half-rounds through the 2K/wave P buffer (same-wave DS order
    // makes the reuse safe; no barrier — Pw is per-wave).
#pragma unroll
    for (int half = 0; half < 2; half++) {
#pragma unroll
      for (int nf = 0; nf < 4; nf++)
        *(bf16x4*)(Pw + l15 * 64 + ((((nf << 1) | (quad >> 1)) ^ swz7) << 3) +
                   ((quad & 1) << 2)) = p4[half * 4 + nf];
      bf16x8 pb0 = *(const bf16x8*)(Pw + l15 * 64 + ((quad ^ swz7) << 3));
      bf16x8 pb1 = *(const bf16x8*)(Pw + l15 * 64 + (((4 + quad) ^ swz7) << 3));
#pragma unroll
      for (int kc = 0; kc < 2; kc++) {
        bf16x8 pb = kc ? pb1 : pb0;
        const int kcg = half * 2 + kc;           // global kt32-chunk 0..3
#pragma unroll
        for (int nf = 0; nf < 4; nf++) {
          bf16x8 vf = *(const bf16x8*)(Vc + (nf * 16 + l15) * 128 +
                                       (((kcg * 4 + quad) ^ l15) << 3));
          o[nf] = __builtin_amdgcn_mfma_f32_16x16x32_bf16(vf, pb, o[nf], 0, 0, 0);
        }
      }
    }
  }

  // epilogue: lane owns q; d = nf*16+quad*4+r -> 4x 8B stores
  const float inv = 1.0f / lsum;
#pragma unroll
  for (int nf = 0; nf < 4; nf++) {
    bf16x4 ov;
#pragma unroll
    for (int r = 0; r < 4; r++) ov[r] = (bf16)(o[nf][r] * inv);
    *(bf16x4*)(O + (size_t)(bb * 2048 + q) * 1024 + h * 64 + nf * 16 + quad * 4) = ov;
  }
}

// ---------------------------------------------------------------- launch
extern "C" void kernel_launch(void* const* d_in, const int* in_sizes, int n_in,
                              void* d_out, int out_size, void* d_ws, size_t ws_size,
                              hipStream_t stream) {
  const float* x     = (const float*)d_in[0];
  const float* Wqkv  = (const float*)d_in[1];
  const float* bqkv  = (const float*)d_in[2];
  const float* Wproj = (const float*)d_in[3];
  const float* bproj = (const float*)d_in[4];
  float* out = (float*)d_out;

  char* p = (char*)d_ws;
  bf16* xbf    = (bf16*)p; p += (size_t)M_ * C_ * 2;     // 8 MB
  bf16* wqkvT  = (bf16*)p; p += (size_t)NQKV * C_ * 2;   // 6 MB
  bf16* wprojT = (bf16*)p; p += (size_t)C_ * C_ * 2;     // 2 MB
  bf16* Qb     = (bf16*)p; p += (size_t)M_ * C_ * 2;     // 8 MB
  bf16* Kb     = (bf16*)p; p += (size_t)M_ * C_ * 2;     // 8 MB
  bf16* Vtb    = (bf16*)p; p += (size_t)M_ * C_ * 2;     // 8 MB
  bf16* AO     = (bf16*)p;                               // 8 MB (total 48 MB)

  cvt_bf16_k<<<M_ * C_ / 1024, 256, 0, stream>>>(x, xbf);
  transpose_cvt<<<dim3(NQKV / 32, C_ / 32), dim3(32, 8), 0, stream>>>(Wqkv, wqkvT, C_, NQKV);
  transpose_cvt<<<dim3(C_ / 32, C_ / 32), dim3(32, 8), 0, stream>>>(Wproj, wprojT, C_, C_);

  gemm_k<0, 64><<<dim3(M_ / 64, NQKV / 128), 256, 0, stream>>>(
      xbf, wqkvT, bqkv, nullptr, Qb, Kb, Vtb);

  attn_k<<<512, 512, 0, stream>>>(Qb, Kb, Vtb, AO);

  gemm_k<1, 64><<<dim3(M_ / 64, C_ / 128), 256, 0, stream>>>(
      AO, wprojT, bproj, out, nullptr, nullptr, nullptr);
}